// Round 12
// baseline (288.807 us; speedup 1.0000x reference)
//
#include <hip/hip_runtime.h>

// CKConv: y[b,o,n] = sum_i (x[b,i] * k[o,i])_causal[n] + bias[o]
// Rank-33 kernel: kr[o,i,t] = sum_r hbT[r][t] * M2[r][i][o]
// FFT path: Yf[b,o,f] = sum_i Xf[b,i,f]*Kf[o,i,f],  Kf = sum_r Hf[r,f]*M2[r,i,o]

#define LSEQ   8192
#define N2     8192      // half-size complex FFT length
#define HDIM   32
#define NB     33        // 32 SIREN basis rows + constant row (for b3)
#define NROWS  512       // B*Ci = 8*64
#define NFREQ  8193      // rfft bins of N=16384
#define FSTRIDE 8200     // complex row stride
#define FBLK   8
#define FTH    1024      // FFT kernel block size
#define OMEGA0 30.0f
#define TWOPI  6.283185307179586f

// padded LDS index: caps bank conflicts at <=4-way across all FFT stages
#define IDX(i) ((i) + ((i) >> 4))

// ---------------------------------------------------------------- prep: SIREN basis
__global__ __launch_bounds__(256) void prep_basis_kernel(
    const float* __restrict__ w1, const float* __restrict__ b1,
    const float* __restrict__ w2, const float* __restrict__ b2,
    float* __restrict__ hbT)   // [NB][LSEQ]; hbT[r][s] = h[L-1-s, r], hbT[32][s] = 1
{
    int t = blockIdx.x * 256 + threadIdx.x;      // grid = 32 blocks
    float rel = -1.0f + 2.0f * (float)t / (float)(LSEQ - 1);
    float h1[HDIM];
    #pragma unroll
    for (int j = 0; j < HDIM; ++j)
        h1[j] = sinf(OMEGA0 * fmaf(rel, w1[j], b1[j]));
    for (int j = 0; j < HDIM; ++j) {
        float acc = b2[j];
        #pragma unroll 8
        for (int j2 = 0; j2 < HDIM; ++j2)
            acc = fmaf(h1[j2], w2[j2 * HDIM + j], acc);
        hbT[j * LSEQ + (LSEQ - 1 - t)] = sinf(OMEGA0 * acc);
    }
    hbT[HDIM * LSEQ + t] = 1.0f;
}

// ---------------------------------------------------------------- prep: M2[r][i][o]
__global__ __launch_bounds__(256) void prep_m2_kernel(
    const float* __restrict__ w3, const float* __restrict__ b3,
    float* __restrict__ M2)
{
    int idx = blockIdx.x * 256 + threadIdx.x;    // 135168 = 33*64*64
    if (idx >= NB * 64 * 64) return;
    int o = idx & 63;
    int i = (idx >> 6) & 63;
    int r = idx >> 12;
    M2[idx] = (r < HDIM) ? w3[r * 4096 + o * 64 + i] : b3[o * 64 + i];
}

// ---------------------------------------------------------------- twiddle helpers
__device__ __forceinline__ float2 tw8k(const float2* Tq, int t)
{
    bool mir = t > 1024;
    int u = mir ? 2048 - t : t;
    float2 e = Tq[u];
    float c = mir ? e.y : e.x;
    float s = mir ? e.x : e.y;
    return make_float2(c, -s);       // W^t = e^{-i*2pi*t/8192}
}

__device__ __forceinline__ void build_table(float2* Tq, int tid)
{
    for (int t = tid; t <= 1024; t += FTH) {
        float s, c;
        __sincosf(TWOPI * (float)t / 8192.0f, &s, &c);
        Tq[t] = make_float2(c, s);
    }
}

// ---------------------------------------------------------------- 8192-pt C2C FFT core
// radix-4 DIF x6 (outputs in (0,2,1,3) order) + final radix-2, then 13-bit reversal.
__device__ __forceinline__ void fft8192_core(float* re, float* im,
                                             const float2* Tq, int tid)
{
    for (int p = 11; p >= 1; p -= 2) {           // m = 2048,512,128,32,8,2
        int m = 1 << p;
        int lmul = 11 - p;
        __syncthreads();
        for (int u = tid; u < 2048; u += FTH) {
            int j = u & (m - 1);
            int base = ((u >> p) << (p + 2)) + j;
            int i0 = IDX(base), i1 = IDX(base + m), i2 = IDX(base + 2 * m), i3 = IDX(base + 3 * m);
            float ar = re[i0], ai = im[i0];
            float br = re[i1], bi = im[i1];
            float cr = re[i2], ci = im[i2];
            float dr = re[i3], di = im[i3];
            float t0r = ar + cr, t0i = ai + ci;
            float t1r = ar - cr, t1i = ai - ci;
            float t2r = br + dr, t2i = bi + di;
            float t3r = br - dr, t3i = bi - di;
            float q0r = t0r + t2r, q0i = t0i + t2i;
            float q2r = t0r - t2r, q2i = t0i - t2i;
            float q1r = t1r + t3i, q1i = t1i - t3r;   // t1 - i*t3
            float q3r = t1r - t3i, q3i = t1i + t3r;   // t1 + i*t3
            float2 w1 = tw8k(Tq, j << lmul);
            float w2r = w1.x * w1.x - w1.y * w1.y;
            float w2i = 2.0f * w1.x * w1.y;
            float w3r = w2r * w1.x - w2i * w1.y;
            float w3i = w2r * w1.y + w2i * w1.x;
            re[i0] = q0r;                     im[i0] = q0i;
            re[i1] = q2r * w2r - q2i * w2i;   im[i1] = q2r * w2i + q2i * w2r;
            re[i2] = q1r * w1.x - q1i * w1.y; im[i2] = q1r * w1.y + q1i * w1.x;
            re[i3] = q3r * w3r - q3i * w3i;   im[i3] = q3r * w3i + q3i * w3r;
        }
    }
    __syncthreads();
    for (int u = tid; u < 4096; u += FTH) {
        int a = IDX(2 * u), b = IDX(2 * u + 1);
        float ar = re[a], ai = im[a];
        float br = re[b], bi = im[b];
        re[a] = ar + br; im[a] = ai + bi;
        re[b] = ar - br; im[b] = ai - bi;
    }
    __syncthreads();
    for (int idx = tid; idx < N2; idx += FTH) {
        unsigned r = __brev((unsigned)idx) >> 19;
        if ((int)r > idx) {
            int pa = IDX(idx), pb = IDX((int)r);
            float tr = re[pa], ti = im[pa];
            re[pa] = re[pb]; im[pa] = im[pb];
            re[pb] = tr;     im[pb] = ti;
        }
    }
    __syncthreads();
}

// ---------------------------------------------------------------- forward rfft of zero-padded length-8192 real rows
__global__ __launch_bounds__(FTH) void rfft_rows_kernel(
    const float* __restrict__ in, float* __restrict__ outF)
{
    __shared__ float re[8704], im[8704];
    __shared__ float2 Tq[1025];
    int tid = threadIdx.x;
    int row = blockIdx.x;

    build_table(Tq, tid);

    const float2* zin = (const float2*)(in + (long long)row * LSEQ);
    for (int n = tid; n < 4096; n += FTH) {
        float2 v = zin[n];
        re[IDX(n)] = v.x;            im[IDX(n)] = v.y;
        re[IDX(n + 4096)] = 0.0f;    im[IDX(n + 4096)] = 0.0f;
    }
    fft8192_core(re, im, Tq, tid);

    float2* out = (float2*)outF + (long long)row * FSTRIDE;
    for (int k = tid; k <= 8192; k += FTH) {
        int k1 = IDX(k & (N2 - 1));
        int k2 = IDX((N2 - k) & (N2 - 1));
        float zr = re[k1], zi = im[k1];
        float wr = re[k2], wi = im[k2];
        float er = 0.5f * (zr + wr), ei = 0.5f * (zi - wi);
        float pr = 0.5f * (zi + wi), pi = 0.5f * (wr - zr);
        float s, c;
        __sincosf(-TWOPI * (float)k / 16384.0f, &s, &c);
        out[k] = make_float2(er + c * pr - s * pi,
                             ei + c * pi + s * pr);
    }
}

// ---------------------------------------------------------------- frequency-domain contraction (in-place on XYf)
// 512 threads = 8 waves. FBLK=8 freqs, i in 8 octants of 8.
// H staged ONCE per block into LDS (block-constant, 2.1 KB).
// K-build: FULL static unroll — 33 independent m loads (registers, one drain)
// + 132 static-offset broadcast ds_read_b128 of Hs + 528 unbroken fma.
// Einsum (round-7): thread owns (o, b=w); 64B-contiguous write-back per row.
__global__ __launch_bounds__(512, 3) void contract_kernel(
    const float* __restrict__ Hf, const float* __restrict__ M2,
    float* __restrict__ XYf)
{
    __shared__ float2 Ks[FBLK][8][64];               // [f][ii][o]  32 KB
    __shared__ __align__(16) float2 Xq[8][8][FBLK];  // [b][ii][f]   4 KB
    __shared__ __align__(16) float2 Hs[NB][FBLK];    // [r][f]     2112 B
    int tid = threadIdx.x;
    int o = tid & 63;
    int w = tid >> 6;                                // wave id 0..7
    long long f0 = (long long)blockIdx.x * FBLK;

    // stage H once per block (block-constant across octants)
    for (int idx = tid; idx < NB * FBLK; idx += 512) {
        int r = idx >> 3, f = idx & 7;
        Hs[r][f] = ((const float2*)Hf)[(size_t)r * FSTRIDE + f0 + f];
    }

    float2 yacc[FBLK];                               // [f] for b = w
    #pragma unroll
    for (int f = 0; f < FBLK; ++f) yacc[f] = make_float2(0.f, 0.f);

    // X staging coords: thread stages one float2 Xq[sb][sii][sf]
    int sf  = tid & 7;
    int sii = (tid >> 3) & 7;
    int sb  = tid >> 6;

    for (int oct = 0; oct < 8; ++oct) {
        __syncthreads();   // prev einsum complete (oct=0: Hs staging complete)

        // issue X stage load early; committed to LDS after K-build
        const float2* xsrc = (const float2*)XYf
            + (long long)((sb << 6) + (oct << 3) + sii) * FSTRIDE + f0 + sf;
        float2 xstage = *xsrc;

        // ---- prefetch all 33 m values: full unroll -> 33 independent loads in regs
        const float* mp = M2 + (oct << 9) + tid;     // M2[r][oct*8+w][o], r stride 4096
        float mv[NB];
        #pragma unroll
        for (int r = 0; r < NB; ++r)
            mv[r] = mp[(size_t)r << 12];

        // ---- K build: full unroll, H via static-offset LDS broadcast reads
        float2 kacc[FBLK];
        #pragma unroll
        for (int f = 0; f < FBLK; ++f) kacc[f] = make_float2(0.f, 0.f);

        #pragma unroll
        for (int r = 0; r < NB; ++r) {
            const float4* hp = (const float4*)(&Hs[r][0]);
            float4 h0 = hp[0], h1 = hp[1], h2 = hp[2], h3 = hp[3];
            float hr_[FBLK] = {h0.x,h0.z,h1.x,h1.z,h2.x,h2.z,h3.x,h3.z};
            float hi_[FBLK] = {h0.y,h0.w,h1.y,h1.w,h2.y,h2.w,h3.y,h3.w};
            #pragma unroll
            for (int f = 0; f < FBLK; ++f) {
                kacc[f].x = fmaf(mv[r], hr_[f], kacc[f].x);
                kacc[f].y = fmaf(mv[r], hi_[f], kacc[f].y);
            }
        }

        // commit staged X and built K to LDS
        Xq[sb][sii][sf] = xstage;
        #pragma unroll
        for (int f = 0; f < FBLK; ++f)
            Ks[f][w][o] = kacc[f];
        __syncthreads();

        // ---- einsum: thread owns (o, b=w)
        #pragma unroll 2
        for (int ii = 0; ii < 8; ++ii) {
            const float4* xp = (const float4*)(&Xq[w][ii][0]);
            float4 x0 = xp[0], x1 = xp[1], x2 = xp[2], x3 = xp[3];
            float xr[FBLK] = {x0.x,x0.z,x1.x,x1.z,x2.x,x2.z,x3.x,x3.z};
            float xi[FBLK] = {x0.y,x0.w,x1.y,x1.w,x2.y,x2.w,x3.y,x3.w};
            #pragma unroll
            for (int f = 0; f < FBLK; ++f) {
                float2 kv = Ks[f][ii][o];
                yacc[f].x = fmaf(xr[f], kv.x, fmaf(-xi[f], kv.y, yacc[f].x));
                yacc[f].y = fmaf(xr[f], kv.y, fmaf( xi[f], kv.x, yacc[f].y));
            }
        }
    }
    __syncthreads();   // all staging reads done before in-place write-back

    // 64B contiguous write-back per thread
    long long row = (long long)((w << 6) + o);
    float2* yp = (float2*)XYf + row * FSTRIDE + f0;
    #pragma unroll
    for (int f = 0; f < FBLK; ++f)
        if (f0 + f < NFREQ) yp[f] = yacc[f];
}

// ---------------------------------------------------------------- inverse rfft + bias, keep first 8192 samples
__global__ __launch_bounds__(FTH) void irfft_rows_kernel(
    const float* __restrict__ Yf, const float* __restrict__ bias,
    float* __restrict__ out)
{
    __shared__ float re[8704], im[8704];
    __shared__ float2 Tq[1025];
    int tid = threadIdx.x;
    int row = blockIdx.x;            // b*64 + o
    int o = row & 63;

    build_table(Tq, tid);

    const float2* G = (const float2*)Yf + (long long)row * FSTRIDE;
    for (int k = tid; k < N2; k += FTH) {
        float2 gk = G[k];
        float2 gm = G[8192 - k];
        float er = 0.5f * (gk.x + gm.x), ei = 0.5f * (gk.y - gm.y);
        float pr = 0.5f * (gk.x - gm.x), pi = 0.5f * (gk.y + gm.y);
        float s, c;
        __sincosf(TWOPI * (float)k / 16384.0f, &s, &c);
        float or_ = pr * c - pi * s;
        float oi_ = pr * s + pi * c;
        re[IDX(k)] = er - oi_;            // Re(Z)
        im[IDX(k)] = -(ei + or_);         // -Im(Z)  (conjugate)
    }
    fft8192_core(re, im, Tq, tid);

    float bo = bias[o];
    const float scale = 1.0f / 8192.0f;
    float2* op = (float2*)(out + (long long)row * LSEQ);
    for (int n = tid; n < 4096; n += FTH) {
        int pn = IDX(n);
        op[n] = make_float2(fmaf(re[pn], scale, bo), fmaf(-im[pn], scale, bo));
    }
}

// ---------------------------------------------------------------- launch
extern "C" void kernel_launch(void* const* d_in, const int* in_sizes, int n_in,
                              void* d_out, int out_size, void* d_ws, size_t ws_size,
                              hipStream_t stream)
{
    const float* x    = (const float*)d_in[0];
    const float* w1   = (const float*)d_in[1];
    const float* b1   = (const float*)d_in[2];
    const float* w2   = (const float*)d_in[3];
    const float* b2   = (const float*)d_in[4];
    const float* w3   = (const float*)d_in[5];
    const float* b3   = (const float*)d_in[6];
    const float* bias = (const float*)d_in[7];
    float* out = (float*)d_out;

    float* ws  = (float*)d_ws;
    float* hbT = ws;                               // NB*LSEQ          = 270336
    float* Hf  = hbT + NB * LSEQ;                  // NB*FSTRIDE*2     = 541200
    float* M2  = Hf + NB * FSTRIDE * 2;            // NB*64*64         = 135168
    float* XYf = M2 + NB * 64 * 64;                // NROWS*FSTRIDE*2  = 8396800

    prep_basis_kernel<<<dim3(LSEQ / 256), dim3(256), 0, stream>>>(w1, b1, w2, b2, hbT);
    prep_m2_kernel<<<dim3((NB * 64 * 64 + 255) / 256), dim3(256), 0, stream>>>(w3, b3, M2);
    rfft_rows_kernel<<<dim3(NB), dim3(FTH), 0, stream>>>(hbT, Hf);
    rfft_rows_kernel<<<dim3(NROWS), dim3(FTH), 0, stream>>>(x, XYf);
    contract_kernel<<<dim3((NFREQ + FBLK - 1) / FBLK), dim3(512), 0, stream>>>(Hf, M2, XYf);
    irfft_rows_kernel<<<dim3(NROWS), dim3(FTH), 0, stream>>>(XYf, bias, out);
}

// Round 13
// 243.632 us; speedup vs baseline: 1.1854x; 1.1854x over previous
//
#include <hip/hip_runtime.h>

// CKConv: y[b,o,n] = sum_i (x[b,i] * k[o,i])_causal[n] + bias[o]
// Rank-33 kernel: kr[o,i,t] = sum_r hbT[r][t] * M2[r][i][o]
// FFT path: Yf[b,o,f] = sum_i Xf[b,i,f]*Kf[o,i,f],  Kf = sum_r Hf[r,f]*M2[r,i,o]

#define LSEQ   8192
#define N2     8192      // half-size complex FFT length
#define HDIM   32
#define NB     33        // 32 SIREN basis rows + constant row (for b3)
#define NROWS  512       // B*Ci = 8*64
#define NFREQ  8193      // rfft bins of N=16384
#define FSTRIDE 8200     // complex row stride
#define FBLK   8
#define FTH    1024      // FFT kernel block size
#define OMEGA0 30.0f
#define TWOPI  6.283185307179586f

// padded LDS index: caps bank conflicts at <=4-way across all FFT stages
#define IDX(i) ((i) + ((i) >> 4))

// ---------------------------------------------------------------- twiddle helpers
__device__ __forceinline__ float2 tw8k(const float2* Tq, int t)
{
    bool mir = t > 1024;
    int u = mir ? 2048 - t : t;
    float2 e = Tq[u];
    float c = mir ? e.y : e.x;
    float s = mir ? e.x : e.y;
    return make_float2(c, -s);       // W^t = e^{-i*2pi*t/8192}
}

__device__ __forceinline__ void build_table(float2* Tq, int tid)
{
    for (int t = tid; t <= 1024; t += FTH) {
        float s, c;
        __sincosf(TWOPI * (float)t / 8192.0f, &s, &c);
        Tq[t] = make_float2(c, s);
    }
}

// ---------------------------------------------------------------- 8192-pt C2C FFT core
// radix-4 DIF x6 (outputs in (0,2,1,3) order) + final radix-2, then 13-bit reversal.
__device__ __forceinline__ void fft8192_core(float* re, float* im,
                                             const float2* Tq, int tid)
{
    for (int p = 11; p >= 1; p -= 2) {           // m = 2048,512,128,32,8,2
        int m = 1 << p;
        int lmul = 11 - p;
        __syncthreads();
        for (int u = tid; u < 2048; u += FTH) {
            int j = u & (m - 1);
            int base = ((u >> p) << (p + 2)) + j;
            int i0 = IDX(base), i1 = IDX(base + m), i2 = IDX(base + 2 * m), i3 = IDX(base + 3 * m);
            float ar = re[i0], ai = im[i0];
            float br = re[i1], bi = im[i1];
            float cr = re[i2], ci = im[i2];
            float dr = re[i3], di = im[i3];
            float t0r = ar + cr, t0i = ai + ci;
            float t1r = ar - cr, t1i = ai - ci;
            float t2r = br + dr, t2i = bi + di;
            float t3r = br - dr, t3i = bi - di;
            float q0r = t0r + t2r, q0i = t0i + t2i;
            float q2r = t0r - t2r, q2i = t0i - t2i;
            float q1r = t1r + t3i, q1i = t1i - t3r;   // t1 - i*t3
            float q3r = t1r - t3i, q3i = t1i + t3r;   // t1 + i*t3
            float2 w1 = tw8k(Tq, j << lmul);
            float w2r = w1.x * w1.x - w1.y * w1.y;
            float w2i = 2.0f * w1.x * w1.y;
            float w3r = w2r * w1.x - w2i * w1.y;
            float w3i = w2r * w1.y + w2i * w1.x;
            re[i0] = q0r;                     im[i0] = q0i;
            re[i1] = q2r * w2r - q2i * w2i;   im[i1] = q2r * w2i + q2i * w2r;
            re[i2] = q1r * w1.x - q1i * w1.y; im[i2] = q1r * w1.y + q1i * w1.x;
            re[i3] = q3r * w3r - q3i * w3i;   im[i3] = q3r * w3i + q3i * w3r;
        }
    }
    __syncthreads();
    for (int u = tid; u < 4096; u += FTH) {
        int a = IDX(2 * u), b = IDX(2 * u + 1);
        float ar = re[a], ai = im[a];
        float br = re[b], bi = im[b];
        re[a] = ar + br; im[a] = ai + bi;
        re[b] = ar - br; im[b] = ai - bi;
    }
    __syncthreads();
    for (int idx = tid; idx < N2; idx += FTH) {
        unsigned r = __brev((unsigned)idx) >> 19;
        if ((int)r > idx) {
            int pa = IDX(idx), pb = IDX((int)r);
            float tr = re[pa], ti = im[pa];
            re[pa] = re[pb]; im[pa] = im[pb];
            re[pb] = tr;     im[pb] = ti;
        }
    }
    __syncthreads();
}

// ---------------------------------------------------------------- merged forward kernel
// blocks 0..32   : inline SIREN basis row (time-reversed) + rfft -> Hf
// blocks 33..544 : x row rfft -> XYf
// blocks 545..676: M2[r][i][o] prep
__global__ __launch_bounds__(FTH) void fwd_kernel(
    const float* __restrict__ x,
    const float* __restrict__ w1, const float* __restrict__ b1,
    const float* __restrict__ w2, const float* __restrict__ b2,
    const float* __restrict__ w3, const float* __restrict__ b3,
    float* __restrict__ Hf, float* __restrict__ XYf, float* __restrict__ M2)
{
    int blk = blockIdx.x;
    int tid = threadIdx.x;

    if (blk >= NB + NROWS) {                     // ---- prep_m2 path
        int idx = (blk - (NB + NROWS)) * FTH + tid;
        if (idx < NB * 64 * 64) {
            int o = idx & 63;
            int i = (idx >> 6) & 63;
            int r = idx >> 12;
            M2[idx] = (r < HDIM) ? w3[r * 4096 + o * 64 + i] : b3[o * 64 + i];
        }
        return;
    }

    __shared__ float re[8704], im[8704];
    __shared__ float2 Tq[1025];
    build_table(Tq, tid);

    float* outF;
    long long orow;
    if (blk < NB) {                              // ---- basis row (inline MLP)
        int r = blk;
        for (int n = tid; n < 4096; n += FTH) {
            re[IDX(n + 4096)] = 0.0f;  im[IDX(n + 4096)] = 0.0f;
        }
        if (r < HDIM) {
            for (int t = tid; t < LSEQ; t += FTH) {
                float rel = -1.0f + 2.0f * (float)t / (float)(LSEQ - 1);
                float acc = b2[r];
                #pragma unroll 8
                for (int j = 0; j < HDIM; ++j)
                    acc = fmaf(sinf(OMEGA0 * fmaf(rel, w1[j], b1[j])), w2[j * HDIM + r], acc);
                float g = sinf(OMEGA0 * acc);
                int s = LSEQ - 1 - t;            // time-reversed position
                if (s & 1) im[IDX(s >> 1)] = g;
                else       re[IDX(s >> 1)] = g;
            }
        } else {                                 // constant row (b3)
            for (int n = tid; n < 4096; n += FTH) {
                re[IDX(n)] = 1.0f;  im[IDX(n)] = 1.0f;
            }
        }
        outF = Hf;  orow = r;
    } else {                                     // ---- x row
        int row = blk - NB;
        const float2* zin = (const float2*)(x + (long long)row * LSEQ);
        for (int n = tid; n < 4096; n += FTH) {
            float2 v = zin[n];
            re[IDX(n)] = v.x;            im[IDX(n)] = v.y;
            re[IDX(n + 4096)] = 0.0f;    im[IDX(n + 4096)] = 0.0f;
        }
        outF = XYf;  orow = row;
    }

    fft8192_core(re, im, Tq, tid);

    // Hermitian fold: G[k] = Ze[k] + W_16384^k * Zo[k], k = 0..8192
    float2* out = (float2*)outF + orow * FSTRIDE;
    for (int k = tid; k <= 8192; k += FTH) {
        int k1 = IDX(k & (N2 - 1));
        int k2 = IDX((N2 - k) & (N2 - 1));
        float zr = re[k1], zi = im[k1];
        float wr = re[k2], wi = im[k2];
        float er = 0.5f * (zr + wr), ei = 0.5f * (zi - wi);
        float pr = 0.5f * (zi + wi), pi = 0.5f * (wr - zr);
        float s, c;
        __sincosf(-TWOPI * (float)k / 16384.0f, &s, &c);
        out[k] = make_float2(er + c * pr - s * pi,
                             ei + c * pi + s * pr);
    }
}

// ---------------------------------------------------------------- frequency-domain contraction (in-place on XYf)
// ROUND-7 VERSION VERBATIM (143 us): 512 threads = 8 waves, FBLK=8, 8 octants.
// K-build: thread (o,w) owns i = oct*8 + w; H rows via block-uniform scalar
// loads, unroll 3. Einsum: thread owns (o, b=w); 64B-contiguous write-back.
__global__ __launch_bounds__(512, 8) void contract_kernel(
    const float* __restrict__ Hf, const float* __restrict__ M2,
    float* __restrict__ XYf)
{
    __shared__ float2 Ks[FBLK][8][64];              // [f][ii][o]  32 KB
    __shared__ __align__(16) float2 Xq[8][8][FBLK]; // [b][ii][f]   4 KB
    int tid = threadIdx.x;
    int o = tid & 63;
    int w = tid >> 6;                               // wave id 0..7
    long long f0 = (long long)blockIdx.x * FBLK;

    const float* Hblk = Hf + (size_t)blockIdx.x * (FBLK * 2);   // uniform base

    float2 yacc[FBLK];
    #pragma unroll
    for (int f = 0; f < FBLK; ++f) yacc[f] = make_float2(0.f, 0.f);

    // X staging coords: thread stages one float2 Xq[sb][sii][sf]
    int sf  = tid & 7;
    int sii = (tid >> 3) & 7;
    int sb  = tid >> 6;

    for (int oct = 0; oct < 8; ++oct) {
        __syncthreads();   // prev einsum complete before Ks/Xq overwrite

        // issue X stage load early; committed to LDS after K-build
        const float2* xsrc = (const float2*)XYf
            + (long long)((sb << 6) + (oct << 3) + sii) * FSTRIDE + f0 + sf;
        float2 xstage = *xsrc;

        // ---- K build: i = oct*8 + w
        float2 kacc[FBLK];
        #pragma unroll
        for (int f = 0; f < FBLK; ++f) kacc[f] = make_float2(0.f, 0.f);

        const float* mp = M2 + (((oct << 3) + w) << 6) + o;
        #pragma unroll 3
        for (int r = 0; r < NB; ++r) {
            // block-uniform H row -> scalar loads (SGPRs)
            const float4* hp = (const float4*)(Hblk + (size_t)r * (size_t)(FSTRIDE * 2));
            float4 h0 = hp[0], h1 = hp[1], h2 = hp[2], h3 = hp[3];
            float m0 = mp[r << 12];
            float hr_[FBLK] = {h0.x,h0.z,h1.x,h1.z,h2.x,h2.z,h3.x,h3.z};
            float hi_[FBLK] = {h0.y,h0.w,h1.y,h1.w,h2.y,h2.w,h3.y,h3.w};
            #pragma unroll
            for (int f = 0; f < FBLK; ++f) {
                kacc[f].x = fmaf(m0, hr_[f], kacc[f].x);
                kacc[f].y = fmaf(m0, hi_[f], kacc[f].y);
            }
        }
        // commit staged X and built K to LDS
        Xq[sb][sii][sf] = xstage;
        #pragma unroll
        for (int f = 0; f < FBLK; ++f)
            Ks[f][w][o] = kacc[f];
        __syncthreads();

        // ---- einsum: thread owns (o, b=w)
        #pragma unroll 2
        for (int ii = 0; ii < 8; ++ii) {
            const float4* xp = (const float4*)(&Xq[w][ii][0]);
            float4 x0 = xp[0], x1 = xp[1], x2 = xp[2], x3 = xp[3];
            float xr[FBLK] = {x0.x,x0.z,x1.x,x1.z,x2.x,x2.z,x3.x,x3.z};
            float xi[FBLK] = {x0.y,x0.w,x1.y,x1.w,x2.y,x2.w,x3.y,x3.w};
            #pragma unroll
            for (int f = 0; f < FBLK; ++f) {
                float2 kv = Ks[f][ii][o];
                yacc[f].x = fmaf(xr[f], kv.x, fmaf(-xi[f], kv.y, yacc[f].x));
                yacc[f].y = fmaf(xr[f], kv.y, fmaf( xi[f], kv.x, yacc[f].y));
            }
        }
    }
    __syncthreads();   // all staging reads done before in-place write-back

    long long row = (long long)((w << 6) + o);
    float2* yp = (float2*)XYf + row * FSTRIDE + f0;
    #pragma unroll
    for (int f = 0; f < FBLK; ++f)
        if (f0 + f < NFREQ) yp[f] = yacc[f];
}

// ---------------------------------------------------------------- inverse rfft + bias, keep first 8192 samples
__global__ __launch_bounds__(FTH) void irfft_rows_kernel(
    const float* __restrict__ Yf, const float* __restrict__ bias,
    float* __restrict__ out)
{
    __shared__ float re[8704], im[8704];
    __shared__ float2 Tq[1025];
    int tid = threadIdx.x;
    int row = blockIdx.x;            // b*64 + o
    int o = row & 63;

    build_table(Tq, tid);

    const float2* G = (const float2*)Yf + (long long)row * FSTRIDE;
    for (int k = tid; k < N2; k += FTH) {
        float2 gk = G[k];
        float2 gm = G[8192 - k];
        float er = 0.5f * (gk.x + gm.x), ei = 0.5f * (gk.y - gm.y);
        float pr = 0.5f * (gk.x - gm.x), pi = 0.5f * (gk.y + gm.y);
        float s, c;
        __sincosf(TWOPI * (float)k / 16384.0f, &s, &c);
        float or_ = pr * c - pi * s;
        float oi_ = pr * s + pi * c;
        re[IDX(k)] = er - oi_;            // Re(Z)
        im[IDX(k)] = -(ei + or_);         // -Im(Z)  (conjugate)
    }
    fft8192_core(re, im, Tq, tid);

    float bo = bias[o];
    const float scale = 1.0f / 8192.0f;
    float2* op = (float2*)(out + (long long)row * LSEQ);
    for (int n = tid; n < 4096; n += FTH) {
        int pn = IDX(n);
        op[n] = make_float2(fmaf(re[pn], scale, bo), fmaf(-im[pn], scale, bo));
    }
}

// ---------------------------------------------------------------- launch
extern "C" void kernel_launch(void* const* d_in, const int* in_sizes, int n_in,
                              void* d_out, int out_size, void* d_ws, size_t ws_size,
                              hipStream_t stream)
{
    const float* x    = (const float*)d_in[0];
    const float* w1   = (const float*)d_in[1];
    const float* b1   = (const float*)d_in[2];
    const float* w2   = (const float*)d_in[3];
    const float* b2   = (const float*)d_in[4];
    const float* w3   = (const float*)d_in[5];
    const float* b3   = (const float*)d_in[6];
    const float* bias = (const float*)d_in[7];
    float* out = (float*)d_out;

    float* ws  = (float*)d_ws;
    float* hbT = ws;                               // (unused slot, kept for layout)
    float* Hf  = hbT + NB * LSEQ;                  // NB*FSTRIDE*2     = 541200
    float* M2  = Hf + NB * FSTRIDE * 2;            // NB*64*64         = 135168
    float* XYf = M2 + NB * 64 * 64;                // NROWS*FSTRIDE*2  = 8396800

    int m2blocks = (NB * 64 * 64 + FTH - 1) / FTH;             // 132
    fwd_kernel<<<dim3(NB + NROWS + m2blocks), dim3(FTH), 0, stream>>>(
        x, w1, b1, w2, b2, w3, b3, Hf, XYf, M2);
    contract_kernel<<<dim3((NFREQ + FBLK - 1) / FBLK), dim3(512), 0, stream>>>(Hf, M2, XYf);
    irfft_rows_kernel<<<dim3(NROWS), dim3(FTH), 0, stream>>>(XYf, bias, out);
}